// Round 14
// baseline (498.074 us; speedup 1.0000x reference)
//
#include <hip/hip_runtime.h>
#include <hip/hip_bf16.h>

typedef unsigned short u16;
typedef unsigned int   u32;
typedef _Float16 f16;
typedef __attribute__((ext_vector_type(4))) float f32x4;
typedef __attribute__((ext_vector_type(16))) float f32x16;
typedef __attribute__((ext_vector_type(8))) short s16x8;
typedef __attribute__((ext_vector_type(8))) f16 f16x8;
typedef __attribute__((ext_vector_type(2))) __fp16 fp16x2;
typedef __attribute__((ext_vector_type(4))) u16 u16x4;
typedef __attribute__((ext_vector_type(8))) u16 u16x8;
typedef __attribute__((ext_vector_type(2))) u32 u32x2;
typedef __attribute__((ext_vector_type(4))) u32 u32x4;

#define DI __device__ __forceinline__

static constexpr int Bb = 2, Ss = 2048, Hh = 16, Dd = 64, Ee = 1024;
static constexpr int Mrows = Bb * Ss;              // 4096
static constexpr size_t NE = (size_t)Mrows * Ee;   // 4 M elems
static constexpr size_t WN = (size_t)Ee * Ee;      // 1 M elems
static constexpr float QSCALE = 0.125f * 1.44269504088896f;  // 1/8 * log2(e)

DI float bf2f(u16 h) { u32 u = ((u32)h) << 16; return __builtin_bit_cast(float, u); }
DI u16 f2bf(float f) {
    u32 u = __builtin_bit_cast(u32, f);
    u32 r = (u + 0x7FFFu + ((u >> 16) & 1u)) >> 16;
    return (u16)r;
}
DI u16 f2h(float f) { f16 h = (f16)f; return __builtin_bit_cast(u16, h); }
DI u32 pkrtz(float a, float b) {
    fp16x2 r = __builtin_amdgcn_cvt_pkrtz(a, b);
    return __builtin_bit_cast(u32, r);
}
DI float ex2(float x) { return __builtin_amdgcn_exp2f(x); }

#define MFMA_BF(a, b, c) __builtin_amdgcn_mfma_f32_16x16x32_bf16((a), (b), (c), 0, 0, 0)
#define MFMA_F16(a, b, c) __builtin_amdgcn_mfma_f32_16x16x32_f16( \
    __builtin_bit_cast(f16x8, (a)), __builtin_bit_cast(f16x8, (b)), (c), 0, 0, 0)
#define MFMA32_BF(a, b, c) __builtin_amdgcn_mfma_f32_32x32x16_bf16((a), (b), (c), 0, 0, 0)
#define MFMA32_F16(a, b, c) __builtin_amdgcn_mfma_f32_32x32x16_f16( \
    __builtin_bit_cast(f16x8, (a)), __builtin_bit_cast(f16x8, (b)), (c), 0, 0, 0)

// async global->LDS, 16B per lane (LDS dest is wave-uniform base + lane*16)
DI void gld16(const u16* g, u16* l) {
    __builtin_amdgcn_global_load_lds((const __attribute__((address_space(1))) void*)g,
                                     (__attribute__((address_space(3))) void*)l, 16, 0, 0);
}

// ---------------- merged prep: split3 (bid<6144) + wprep (bid>=6144) ----------------
__global__ __launch_bounds__(256) void k_prep(
    const float* __restrict__ q, const float* __restrict__ k, const float* __restrict__ v,
    u16* __restrict__ qh, u16* __restrict__ ql,
    u16* __restrict__ kh, u16* __restrict__ kl, u16* __restrict__ vh,
    const float* __restrict__ Wq, const float* __restrict__ Wk,
    const float* __restrict__ Wv, const float* __restrict__ Wo,
    u16* __restrict__ WqTh, u16* __restrict__ WqTl,
    u16* __restrict__ WkTh, u16* __restrict__ WkTl,
    u16* __restrict__ WvT, u16* __restrict__ WoT) {
    __shared__ float Ts[64 * 65];
    const int bid = blockIdx.x;
    if (bid < 6144) {
        const int y = bid >> 11;
        size_t i = ((size_t)(bid & 2047) * 256 + threadIdx.x) * 8;
        if (y == 2) {
            f32x4 a = *(const f32x4*)(v + i);
            f32x4 b2 = *(const f32x4*)(v + i + 4);
            u16x8 o_;
#pragma unroll
            for (int j = 0; j < 4; j++) { o_[j] = f2h(a[j]); o_[4 + j] = f2h(b2[j]); }
            *(u16x8*)(vh + i) = o_;
            return;
        }
        const float* s = y ? k : q;
        u16* h = y ? kh : qh;
        u16* l = y ? kl : ql;
        f32x4 a = *(const f32x4*)(s + i);
        f32x4 b2 = *(const f32x4*)(s + i + 4);
        u16x8 oh, ol;
#pragma unroll
        for (int j = 0; j < 4; j++) {
            u16 hh = f2bf(a[j]); oh[j] = hh; ol[j] = f2bf(a[j] - bf2f(hh));
            u16 h2 = f2bf(b2[j]); oh[4 + j] = h2; ol[4 + j] = f2bf(b2[j] - bf2f(h2));
        }
        *(u16x8*)(h + i) = oh;
        *(u16x8*)(l + i) = ol;
        return;
    }
    const int t2 = bid - 6144;
    const int y = t2 >> 8;
    const int bx = t2 & 255;
    const int ti = bx >> 4, tj = bx & 15;
    const float* W = (y == 0) ? Wq : (y == 1) ? Wk : (y == 2) ? Wv : Wo;
    const int t = threadIdx.x;
    const int col = t & 63, rb = (t >> 6) * 16;
#pragma unroll
    for (int rr = 0; rr < 16; rr++) {
        int row = rb + rr;
        float vv = (y < 3) ? W[(size_t)ti * 65536 + (size_t)(tj * 64 + row) * 64 + col]
                           : W[(size_t)(tj * 64 + row) * Ee + ti * 64 + col];
        Ts[row * 65 + col] = vv;
    }
    __syncthreads();
#pragma unroll
    for (int rr = 0; rr < 16; rr++) {
        int orow = rb + rr;
        int ocol = col;
        float vv = Ts[ocol * 65 + orow];
        size_t oidx = (size_t)(ti * 64 + orow) * Ee + tj * 64 + ocol;
        if (y == 0) {
            u16 hh = f2bf(vv); WqTh[oidx] = hh; WqTl[oidx] = f2bf(vv - bf2f(hh));
        } else if (y == 1) {
            u16 hh = f2bf(vv); WkTh[oidx] = hh; WkTl[oidx] = f2bf(vv - bf2f(hh));
        } else if (y == 2) {
            WvT[oidx] = f2h(vv);
        } else {
            WoT[oidx] = f2h(vv);
        }
    }
}

// ---------------- GEMM body, 128(M) x 128(N) tile (m97 structure) ----------------
template <int SPLIT, int F16, int OUTMODE>
DI void gemm_body(const u16* __restrict__ Ah, const u16* __restrict__ Al,
                  const u16* __restrict__ Bh, const u16* __restrict__ Bl,
                  const float* __restrict__ bias,
                  u16* __restrict__ C16h, u16* __restrict__ C16l, float* __restrict__ Cf,
                  float scale, u16* As0, u16* As1, u16* Bs0, u16* Bs1) {
    constexpr int M = Mrows, N = Ee, K = Ee;
    const int tid = threadIdx.x;
    const int wave = tid >> 6, lane = tid & 63;
    const int quad = lane >> 4, l16 = lane & 15;
    const int m0 = blockIdx.y * 128, n0 = blockIdx.x * 128;
    const int wm = (wave >> 1) * 64, wn = (wave & 1) * 64;

    f32x4 acc[4][4];
#pragma unroll
    for (int i = 0; i < 4; i++)
#pragma unroll
        for (int j = 0; j < 4; j++) acc[i][j] = (f32x4)0.0f;

    for (int kk = 0; kk < K; kk += 32) {
        __syncthreads();
#pragma unroll
        for (int i = 0; i < 2; i++) {
            int c = tid + i * 256;
            int row = c >> 2, j = c & 3;
            size_t ga = (size_t)(m0 + row) * K + kk + j * 8;
            gld16(Ah + ga, As0 + c * 8);
            if constexpr (SPLIT) gld16(Al + ga, As1 + c * 8);
            size_t gb = (size_t)(n0 + row) * K + kk + j * 8;
            gld16(Bh + gb, Bs0 + c * 8);
            if constexpr (SPLIT) gld16(Bl + gb, Bs1 + c * 8);
        }
        __syncthreads();

        s16x8 bf[4][2];
#pragma unroll
        for (int nt = 0; nt < 4; nt++) {
            int r = wn + nt * 16 + l16;
            bf[nt][0] = *(const s16x8*)&Bs0[r * 32 + quad * 8];
            if constexpr (SPLIT) bf[nt][1] = *(const s16x8*)&Bs1[r * 32 + quad * 8];
        }
#pragma unroll
        for (int mt = 0; mt < 4; mt++) {
            int r = wm + mt * 16 + l16;
            s16x8 a0 = *(const s16x8*)&As0[r * 32 + quad * 8];
            s16x8 a1;
            if constexpr (SPLIT) a1 = *(const s16x8*)&As1[r * 32 + quad * 8];
#pragma unroll
            for (int nt = 0; nt < 4; nt++) {
                if constexpr (F16) {
                    acc[mt][nt] = MFMA_F16(a0, bf[nt][0], acc[mt][nt]);
                } else {
                    acc[mt][nt] = MFMA_BF(a0, bf[nt][0], acc[mt][nt]);
                    if constexpr (SPLIT) {
                        acc[mt][nt] = MFMA_BF(a0, bf[nt][1], acc[mt][nt]);
                        acc[mt][nt] = MFMA_BF(a1, bf[nt][0], acc[mt][nt]);
                    }
                }
            }
        }
    }

#pragma unroll
    for (int mt = 0; mt < 4; mt++)
#pragma unroll
        for (int nt = 0; nt < 4; nt++) {
            int gn = n0 + wn + nt * 16 + l16;
            float bs = bias[gn];
            if constexpr (OUTMODE == 1) {
                int gm = m0 + wm + mt * 16 + quad * 4;
                u16x4 pk;
#pragma unroll
                for (int r = 0; r < 4; r++) pk[r] = f2h((acc[mt][nt][r] + bs) * scale);
                *(u16x4*)&C16h[(size_t)gn * M + gm] = pk;
            } else {
#pragma unroll
                for (int r = 0; r < 4; r++) {
                    int gm = m0 + wm + mt * 16 + quad * 4 + r;
                    float v = (acc[mt][nt][r] + bs) * scale;
                    if constexpr (OUTMODE == 0) {
                        Cf[(size_t)gm * N + gn] = v;
                    } else {
                        u16 hh = f2bf(v);
                        C16h[(size_t)gm * N + gn] = hh;
                        C16l[(size_t)gm * N + gn] = f2bf(v - bf2f(hh));
                    }
                }
            }
        }
}

// ---------------- fused Q/K/V projections (grid.z selects) ----------------
__global__ __launch_bounds__(256, 3) void k_qkv(
    const u16* __restrict__ qh, const u16* __restrict__ ql,
    const u16* __restrict__ kh, const u16* __restrict__ kl,
    const u16* __restrict__ vh,
    const u16* __restrict__ WqTh, const u16* __restrict__ WqTl,
    const u16* __restrict__ WkTh, const u16* __restrict__ WkTl,
    const u16* __restrict__ WvT,
    const float* __restrict__ bq, const float* __restrict__ bk, const float* __restrict__ bv,
    u16* __restrict__ Qh, u16* __restrict__ Ql2,
    u16* __restrict__ Kh, u16* __restrict__ Kl2, u16* __restrict__ Vt) {
    __shared__ u16 As[2][128 * 32];
    __shared__ u16 Bs[2][128 * 32];
    int z = blockIdx.z;
    if (z == 0)
        gemm_body<1, 0, 2>(qh, ql, WqTh, WqTl, bq, Qh, Ql2, nullptr, QSCALE,
                           As[0], As[1], Bs[0], Bs[1]);
    else if (z == 1)
        gemm_body<1, 0, 2>(kh, kl, WkTh, WkTl, bk, Kh, Kl2, nullptr, 1.0f,
                           As[0], As[1], Bs[0], Bs[1]);
    else
        gemm_body<0, 1, 1>(vh, nullptr, WvT, nullptr, bv, Vt, nullptr, nullptr, 1.0f,
                           As[0], As[1], Bs[0], Bs[1]);
}

// ---------------- output projection: ctx(fp16) @ WoT(fp16) + bo -> f32 ----------------
__global__ __launch_bounds__(256, 3) void k_out(
    const u16* __restrict__ ctx, const u16* __restrict__ WoT,
    const float* __restrict__ bo, float* __restrict__ out) {
    __shared__ u16 As[128 * 32];
    __shared__ u16 Bs[128 * 32];
    gemm_body<0, 1, 0>(ctx, nullptr, WoT, nullptr, bo, nullptr, nullptr, out, 1.0f,
                       As, nullptr, Bs, nullptr);
}

// ---------------- flash attention: 2-way split-t + in-kernel merge ------------------
// r20: r19 counters show no pipe saturated (Mfma 35, VALU 37, LDS ~37%, HBM 4%)
// but Occupancy 18.5% — grid-limited to 2 blocks/CU (512 blocks) though LDS 49KB
// admits 3. Split t into 2 halves -> 1024 blocks -> 3 blocks/CU = 3 waves/SIMD.
// Merge: both halves write unnormalized (o,m,l) to dead ws (qh..vh region, dead
// after k_qkv); threadfence + atomicAdd counter; first finisher exits, second
// merges against LIVE regs and writes ctx (exact 2-way online-softmax combine).
// Halves of same (bh,qt) share XCD (bid%8) -> partials are L2-local.
__global__ __launch_bounds__(256, 3) void k_attn(
    const u16* __restrict__ Qh, const u16* __restrict__ Ql,
    const u16* __restrict__ Kh, const u16* __restrict__ Kl,
    const u16* __restrict__ Vt, u16* __restrict__ ctx,
    float* __restrict__ pO, float* __restrict__ pML, u32* __restrict__ cnt) {
    const int bh = blockIdx.x;
    const int b = bh >> 4, h = bh & 15;
    const int q0 = blockIdx.y * 128;
    const int z = blockIdx.z;               // t-half
    const int rowBase = b * Ss + q0;
    const int hc = h * 64;
    const int tStart = z * (Ss / 2), tEnd = tStart + Ss / 2;

    __shared__ u16 Ks[2][2][64 * 64];  // [buf][plane][row*64 + chunk] (32 KB)
    __shared__ u16 Vs[2][64 * 64];     // [buf][row*64 + chunk] fp16 (16 KB)
    __shared__ u32 sOld;

    const int tid = threadIdx.x;
    const int wave = tid >> 6, lane = tid & 63;
    const int l31 = lane & 31, hi = lane >> 5;
    const int swl = l31 & 7;

    // ---- staging: linear LDS dest, inverse-swizzled global source (rule #21)
    const int c0 = tid, c1 = tid + 256;
    const int srow0 = c0 >> 3, sj0 = (c0 & 7) ^ (srow0 & 7);
    const int srow1 = c1 >> 3, sj1 = (c1 & 7) ^ (srow1 & 7);

    auto stage = [&](int t0, int bf) {
        const size_t kb = (size_t)(b * Ss + t0) * Ee + hc;
        const size_t vb0 = (size_t)(hc + srow0) * Mrows + b * Ss + t0;
        const size_t vb1 = (size_t)(hc + srow1) * Mrows + b * Ss + t0;
        gld16(Kh + kb + (size_t)srow0 * Ee + sj0 * 8, &Ks[bf][0][c0 * 8]);
        gld16(Kh + kb + (size_t)srow1 * Ee + sj1 * 8, &Ks[bf][0][c1 * 8]);
        gld16(Kl + kb + (size_t)srow0 * Ee + sj0 * 8, &Ks[bf][1][c0 * 8]);
        gld16(Kl + kb + (size_t)srow1 * Ee + sj1 * 8, &Ks[bf][1][c1 * 8]);
        gld16(Vt + vb0 + sj0 * 8, &Vs[bf][c0 * 8]);
        gld16(Vt + vb1 + sj1 * 8, &Vs[bf][c1 * 8]);
    };

    // loop-invariant Q B-frags: col q = l31, k = d = ks*16 + hi*8 + e
    s16x8 bqh[4], bql[4];
    {
        const size_t qoff = (size_t)(rowBase + wave * 32 + l31) * Ee + hc + hi * 8;
#pragma unroll
        for (int ks = 0; ks < 4; ks++) {
            bqh[ks] = *(const s16x8*)(Qh + qoff + ks * 16);
            bql[ks] = *(const s16x8*)(Ql + qoff + ks * 16);
        }
    }

    f32x16 o[2];   // [dt]: O^T row d = (r&3)+8*(r>>2)+4*hi+32*dt, col q = l31
    o[0] = (f32x16)0.0f;
    o[1] = (f32x16)0.0f;
    float m_ = -1e30f, l_ = 0.f;

    stage(tStart, 0);
    __syncthreads();

    for (int t0 = tStart; t0 < tEnd; t0 += 64) {
        const int p = (t0 >> 6) & 1;
        if (t0 + 64 < tEnd) stage(t0 + 64, p ^ 1);

        const u16* Kp = &Ks[p][0][0];
        const u16* Vp = &Vs[p][0];

        // S^T = K.Q^T (split): st[mt] row t = crow(r,hi)+32*mt, col q = l31
        f32x16 st[2];
        st[0] = (f32x16)0.0f;
        st[1] = (f32x16)0.0f;
        __builtin_amdgcn_s_setprio(1);
#pragma unroll
        for (int mt = 0; mt < 2; mt++) {
            const int rb = (mt * 32 + l31) * 64;
#pragma unroll
            for (int ks = 0; ks < 4; ks++) {
                const int sj = ((2 * ks + hi) ^ swl) * 8;
                s16x8 akh = *(const s16x8*)(Kp + rb + sj);
                s16x8 akl = *(const s16x8*)(Kp + rb + sj + 4096);
                st[mt] = MFMA32_BF(akh, bqh[ks], st[mt]);
                st[mt] = MFMA32_BF(akh, bql[ks], st[mt]);
                st[mt] = MFMA32_BF(akl, bqh[ks], st[mt]);
            }
        }
        __builtin_amdgcn_s_setprio(0);

        // online softmax: q = l31 (lane-local), partner rows live in lane^32
        float tmax = st[0][0];
#pragma unroll
        for (int mt = 0; mt < 2; mt++)
#pragma unroll
            for (int r = 0; r < 16; r++) tmax = fmaxf(tmax, st[mt][r]);
        tmax = fmaxf(tmax, __shfl_xor(tmax, 32));
        float mnew = fmaxf(m_, tmax);
        float al = ex2(m_ - mnew);
        m_ = mnew;
        float psum = 0.f;
#pragma unroll
        for (int mt = 0; mt < 2; mt++)
#pragma unroll
            for (int r = 0; r < 16; r++) {
                st[mt][r] = ex2(st[mt][r] - mnew);
                psum += st[mt][r];
            }
        psum += __shfl_xor(psum, 32);
        l_ = l_ * al + psum;
        o[0] *= al;
        o[1] *= al;

        // P -> PV B-frags in registers: 16 cvt_pkrtz + 8 permlane32_swap
        s16x8 pa[4];
#pragma unroll
        for (int kt = 0; kt < 4; kt++) {
            const int G0 = 2 * kt, G1 = 2 * kt + 1;
            const int m0_ = G0 >> 2, r0_ = (G0 & 3) * 4;
            const int m1_ = G1 >> 2, r1_ = (G1 & 3) * 4;
            u32 wA0 = pkrtz(st[m0_][r0_ + 0], st[m0_][r0_ + 1]);
            u32 wB0 = pkrtz(st[m0_][r0_ + 2], st[m0_][r0_ + 3]);
            u32 wA1 = pkrtz(st[m1_][r1_ + 0], st[m1_][r1_ + 1]);
            u32 wB1 = pkrtz(st[m1_][r1_ + 2], st[m1_][r1_ + 3]);
            u32x2 rA = __builtin_amdgcn_permlane32_swap(wA0, wA1, false, false);
            u32x2 rB = __builtin_amdgcn_permlane32_swap(wB0, wB1, false, false);
            u32x4 w;
            w[0] = rA[0]; w[1] = rB[0]; w[2] = rA[1]; w[3] = rB[1];
            pa[kt] = __builtin_bit_cast(s16x8, w);
        }

        // O^T += V^T . P^T : A = V^T (row d, k t), B = pa (col q, k t)
        __builtin_amdgcn_s_setprio(1);
#pragma unroll
        for (int dt = 0; dt < 2; dt++) {
            const int rbv = (dt * 32 + l31) * 64;
#pragma unroll
            for (int kt = 0; kt < 4; kt++) {
                const int sj = ((2 * kt + hi) ^ swl) * 8;
                s16x8 av = *(const s16x8*)(Vp + rbv + sj);
                o[dt] = MFMA32_F16(av, pa[kt], o[dt]);
            }
        }
        __builtin_amdgcn_s_setprio(0);

        __syncthreads();   // drains this iter's stage (vmcnt(0)) + flips buffer
    }

    // ---- write partial, rendezvous, second finisher merges ----
    const int qt = blockIdx.y;
    const size_t slot = ((((size_t)bh * 16 + qt) * 2 + z) * 256 + tid);
    float* po = pO + slot * 32;
    *(f32x16*)(po) = o[0];
    *(f32x16*)(po + 16) = o[1];
    pML[slot * 2 + 0] = m_;
    pML[slot * 2 + 1] = l_;
    __threadfence();
    if (tid == 0) sOld = atomicAdd(&cnt[bh * 16 + qt], 1u);
    __syncthreads();
    if (sOld == 0) return;          // first finisher: partial only
    __threadfence();                // acquire: other half's writes visible
    const size_t oslot = ((((size_t)bh * 16 + qt) * 2 + (z ^ 1)) * 256 + tid);
    const float* qo = pO + oslot * 32;
    f32x16 o2a = *(const f32x16*)(qo);
    f32x16 o2b = *(const f32x16*)(qo + 16);
    float m2 = pML[oslot * 2 + 0];
    float l2 = pML[oslot * 2 + 1];
    float M = fmaxf(m_, m2);
    float w1 = ex2(m_ - M), w2 = ex2(m2 - M);
    float inv = 1.0f / (l_ * w1 + l2 * w2);
    w1 *= inv; w2 *= inv;
    o[0] = o[0] * w1 + o2a * w2;
    o[1] = o[1] * w1 + o2b * w2;

    // epilogue: ctx[q][hc+d] fp16, d = j + 8g + 4hi + 32dt -> 8B packed stores
    const size_t obase = (size_t)(rowBase + wave * 32 + l31) * Ee + hc + hi * 4;
#pragma unroll
    for (int dt = 0; dt < 2; dt++)
#pragma unroll
        for (int g = 0; g < 4; g++) {
            u32x2 pk;
            pk[0] = pkrtz(o[dt][g * 4 + 0], o[dt][g * 4 + 1]);
            pk[1] = pkrtz(o[dt][g * 4 + 2], o[dt][g * 4 + 3]);
            *(u32x2*)&ctx[obase + dt * 32 + g * 8] = pk;
        }
}

extern "C" void kernel_launch(void* const* d_in, const int* in_sizes, int n_in,
                              void* d_out, int out_size, void* d_ws, size_t ws_size,
                              hipStream_t stream) {
    const float* q   = (const float*)d_in[0];
    const float* kin = (const float*)d_in[1];
    const float* v   = (const float*)d_in[2];
    const float* Wq  = (const float*)d_in[3];
    const float* Wk  = (const float*)d_in[4];
    const float* Wv  = (const float*)d_in[5];
    const float* bq  = (const float*)d_in[6];
    const float* bk  = (const float*)d_in[7];
    const float* bv  = (const float*)d_in[8];
    const float* Wo  = (const float*)d_in[9];
    const float* bo  = (const float*)d_in[10];

    u16* ws = (u16*)d_ws;
    u16 *qh = ws,          *ql = ws + NE,     *kh = ws + 2 * NE, *kl = ws + 3 * NE;
    u16 *vh = ws + 4 * NE;
    u16 *Qh = ws + 5 * NE, *Ql = ws + 6 * NE, *Kh = ws + 7 * NE, *Kl = ws + 8 * NE;
    u16 *Vt = ws + 9 * NE, *ctx = ws + 10 * NE;
    u16 *WqTh = ws + 11 * NE;
    u16 *WqTl = WqTh + WN, *WkTh = WqTh + 2 * WN, *WkTl = WqTh + 3 * WN;
    u16 *WvT = WqTh + 4 * WN, *WoT = WqTh + 5 * WN;

    // attn partials overlay the qh..vh region (dead after k_qkv):
    // pO: 262144 slots x 32 f32 = 33.6 MB at ws+0; pML: 2 MB at ws+36MB;
    // cnt: 512 u32 at ws+38MB. All inside the 40 MB qh..vh region.
    float* pO  = (float*)ws;
    float* pML = (float*)(ws + ((size_t)18 << 20));
    u32*  cnt  = (u32*) (ws + ((size_t)19 << 20));

    dim3 b256(256);
    k_prep<<<dim3(6144 + 1024), b256, 0, stream>>>(q, kin, v, qh, ql, kh, kl, vh,
                                                   Wq, Wk, Wv, Wo,
                                                   WqTh, WqTl, WkTh, WkTl, WvT, WoT);

    k_qkv<<<dim3(8, 32, 3), b256, 0, stream>>>(qh, ql, kh, kl, vh,
                                               WqTh, WqTl, WkTh, WkTl, WvT,
                                               bq, bk, bv, Qh, Ql, Kh, Kl, Vt);

    hipMemsetAsync(cnt, 0, 512 * sizeof(u32), stream);

    k_attn<<<dim3(Bb * Hh, Ss / 128, 2), b256, 0, stream>>>(Qh, Ql, Kh, Kl, Vt, ctx,
                                                            pO, pML, cnt);

    k_out<<<dim3(8, 32), b256, 0, stream>>>(ctx, WoT, bo, (float*)d_out);
}

// Round 15
// 278.944 us; speedup vs baseline: 1.7856x; 1.7856x over previous
//
#include <hip/hip_runtime.h>
#include <hip/hip_bf16.h>

typedef unsigned short u16;
typedef unsigned int   u32;
typedef _Float16 f16;
typedef __attribute__((ext_vector_type(4))) float f32x4;
typedef __attribute__((ext_vector_type(16))) float f32x16;
typedef __attribute__((ext_vector_type(8))) short s16x8;
typedef __attribute__((ext_vector_type(8))) f16 f16x8;
typedef __attribute__((ext_vector_type(2))) __fp16 fp16x2;
typedef __attribute__((ext_vector_type(4))) u16 u16x4;
typedef __attribute__((ext_vector_type(8))) u16 u16x8;
typedef __attribute__((ext_vector_type(2))) u32 u32x2;
typedef __attribute__((ext_vector_type(4))) u32 u32x4;

#define DI __device__ __forceinline__

static constexpr int Bb = 2, Ss = 2048, Hh = 16, Dd = 64, Ee = 1024;
static constexpr int Mrows = Bb * Ss;              // 4096
static constexpr size_t NE = (size_t)Mrows * Ee;   // 4 M elems
static constexpr size_t WN = (size_t)Ee * Ee;      // 1 M elems
static constexpr float QSCALE = 0.125f * 1.44269504088896f;  // 1/8 * log2(e)

DI float bf2f(u16 h) { u32 u = ((u32)h) << 16; return __builtin_bit_cast(float, u); }
DI u16 f2bf(float f) {
    u32 u = __builtin_bit_cast(u32, f);
    u32 r = (u + 0x7FFFu + ((u >> 16) & 1u)) >> 16;
    return (u16)r;
}
DI u16 f2h(float f) { f16 h = (f16)f; return __builtin_bit_cast(u16, h); }
DI u32 pkrtz(float a, float b) {
    fp16x2 r = __builtin_amdgcn_cvt_pkrtz(a, b);
    return __builtin_bit_cast(u32, r);
}
DI float ex2(float x) { return __builtin_amdgcn_exp2f(x); }

#define MFMA_BF(a, b, c) __builtin_amdgcn_mfma_f32_16x16x32_bf16((a), (b), (c), 0, 0, 0)
#define MFMA_F16(a, b, c) __builtin_amdgcn_mfma_f32_16x16x32_f16( \
    __builtin_bit_cast(f16x8, (a)), __builtin_bit_cast(f16x8, (b)), (c), 0, 0, 0)
#define MFMA32_BF(a, b, c) __builtin_amdgcn_mfma_f32_32x32x16_bf16((a), (b), (c), 0, 0, 0)
#define MFMA32_F16(a, b, c) __builtin_amdgcn_mfma_f32_32x32x16_f16( \
    __builtin_bit_cast(f16x8, (a)), __builtin_bit_cast(f16x8, (b)), (c), 0, 0, 0)

// async global->LDS, 16B per lane (LDS dest is wave-uniform base + lane*16)
DI void gld16(const u16* g, u16* l) {
    __builtin_amdgcn_global_load_lds((const __attribute__((address_space(1))) void*)g,
                                     (__attribute__((address_space(3))) void*)l, 16, 0, 0);
}

// ---------------- merged prep: split3 (bid<6144) + wprep (bid>=6144) ----------------
__global__ __launch_bounds__(256) void k_prep(
    const float* __restrict__ q, const float* __restrict__ k, const float* __restrict__ v,
    u16* __restrict__ qh, u16* __restrict__ ql,
    u16* __restrict__ kh, u16* __restrict__ kl, u16* __restrict__ vh,
    const float* __restrict__ Wq, const float* __restrict__ Wk,
    const float* __restrict__ Wv, const float* __restrict__ Wo,
    u16* __restrict__ WqTh, u16* __restrict__ WqTl,
    u16* __restrict__ WkTh, u16* __restrict__ WkTl,
    u16* __restrict__ WvT, u16* __restrict__ WoT) {
    __shared__ float Ts[64 * 65];
    const int bid = blockIdx.x;
    if (bid < 6144) {
        const int y = bid >> 11;
        size_t i = ((size_t)(bid & 2047) * 256 + threadIdx.x) * 8;
        if (y == 2) {
            f32x4 a = *(const f32x4*)(v + i);
            f32x4 b2 = *(const f32x4*)(v + i + 4);
            u16x8 o_;
#pragma unroll
            for (int j = 0; j < 4; j++) { o_[j] = f2h(a[j]); o_[4 + j] = f2h(b2[j]); }
            *(u16x8*)(vh + i) = o_;
            return;
        }
        const float* s = y ? k : q;
        u16* h = y ? kh : qh;
        u16* l = y ? kl : ql;
        f32x4 a = *(const f32x4*)(s + i);
        f32x4 b2 = *(const f32x4*)(s + i + 4);
        u16x8 oh, ol;
#pragma unroll
        for (int j = 0; j < 4; j++) {
            u16 hh = f2bf(a[j]); oh[j] = hh; ol[j] = f2bf(a[j] - bf2f(hh));
            u16 h2 = f2bf(b2[j]); oh[4 + j] = h2; ol[4 + j] = f2bf(b2[j] - bf2f(h2));
        }
        *(u16x8*)(h + i) = oh;
        *(u16x8*)(l + i) = ol;
        return;
    }
    const int t2 = bid - 6144;
    const int y = t2 >> 8;
    const int bx = t2 & 255;
    const int ti = bx >> 4, tj = bx & 15;
    const float* W = (y == 0) ? Wq : (y == 1) ? Wk : (y == 2) ? Wv : Wo;
    const int t = threadIdx.x;
    const int col = t & 63, rb = (t >> 6) * 16;
#pragma unroll
    for (int rr = 0; rr < 16; rr++) {
        int row = rb + rr;
        float vv = (y < 3) ? W[(size_t)ti * 65536 + (size_t)(tj * 64 + row) * 64 + col]
                           : W[(size_t)(tj * 64 + row) * Ee + ti * 64 + col];
        Ts[row * 65 + col] = vv;
    }
    __syncthreads();
#pragma unroll
    for (int rr = 0; rr < 16; rr++) {
        int orow = rb + rr;
        int ocol = col;
        float vv = Ts[ocol * 65 + orow];
        size_t oidx = (size_t)(ti * 64 + orow) * Ee + tj * 64 + ocol;
        if (y == 0) {
            u16 hh = f2bf(vv); WqTh[oidx] = hh; WqTl[oidx] = f2bf(vv - bf2f(hh));
        } else if (y == 1) {
            u16 hh = f2bf(vv); WkTh[oidx] = hh; WkTl[oidx] = f2bf(vv - bf2f(hh));
        } else if (y == 2) {
            WvT[oidx] = f2h(vv);
        } else {
            WoT[oidx] = f2h(vv);
        }
    }
}

// ---------------- GEMM body, 128(M) x 128(N) tile (m97 structure) ----------------
template <int SPLIT, int F16, int OUTMODE>
DI void gemm_body(const u16* __restrict__ Ah, const u16* __restrict__ Al,
                  const u16* __restrict__ Bh, const u16* __restrict__ Bl,
                  const float* __restrict__ bias,
                  u16* __restrict__ C16h, u16* __restrict__ C16l, float* __restrict__ Cf,
                  float scale, u16* As0, u16* As1, u16* Bs0, u16* Bs1) {
    constexpr int M = Mrows, N = Ee, K = Ee;
    const int tid = threadIdx.x;
    const int wave = tid >> 6, lane = tid & 63;
    const int quad = lane >> 4, l16 = lane & 15;
    const int m0 = blockIdx.y * 128, n0 = blockIdx.x * 128;
    const int wm = (wave >> 1) * 64, wn = (wave & 1) * 64;

    f32x4 acc[4][4];
#pragma unroll
    for (int i = 0; i < 4; i++)
#pragma unroll
        for (int j = 0; j < 4; j++) acc[i][j] = (f32x4)0.0f;

    for (int kk = 0; kk < K; kk += 32) {
        __syncthreads();
#pragma unroll
        for (int i = 0; i < 2; i++) {
            int c = tid + i * 256;
            int row = c >> 2, j = c & 3;
            size_t ga = (size_t)(m0 + row) * K + kk + j * 8;
            gld16(Ah + ga, As0 + c * 8);
            if constexpr (SPLIT) gld16(Al + ga, As1 + c * 8);
            size_t gb = (size_t)(n0 + row) * K + kk + j * 8;
            gld16(Bh + gb, Bs0 + c * 8);
            if constexpr (SPLIT) gld16(Bl + gb, Bs1 + c * 8);
        }
        __syncthreads();

        s16x8 bf[4][2];
#pragma unroll
        for (int nt = 0; nt < 4; nt++) {
            int r = wn + nt * 16 + l16;
            bf[nt][0] = *(const s16x8*)&Bs0[r * 32 + quad * 8];
            if constexpr (SPLIT) bf[nt][1] = *(const s16x8*)&Bs1[r * 32 + quad * 8];
        }
#pragma unroll
        for (int mt = 0; mt < 4; mt++) {
            int r = wm + mt * 16 + l16;
            s16x8 a0 = *(const s16x8*)&As0[r * 32 + quad * 8];
            s16x8 a1;
            if constexpr (SPLIT) a1 = *(const s16x8*)&As1[r * 32 + quad * 8];
#pragma unroll
            for (int nt = 0; nt < 4; nt++) {
                if constexpr (F16) {
                    acc[mt][nt] = MFMA_F16(a0, bf[nt][0], acc[mt][nt]);
                } else {
                    acc[mt][nt] = MFMA_BF(a0, bf[nt][0], acc[mt][nt]);
                    if constexpr (SPLIT) {
                        acc[mt][nt] = MFMA_BF(a0, bf[nt][1], acc[mt][nt]);
                        acc[mt][nt] = MFMA_BF(a1, bf[nt][0], acc[mt][nt]);
                    }
                }
            }
        }
    }

#pragma unroll
    for (int mt = 0; mt < 4; mt++)
#pragma unroll
        for (int nt = 0; nt < 4; nt++) {
            int gn = n0 + wn + nt * 16 + l16;
            float bs = bias[gn];
            if constexpr (OUTMODE == 1) {
                int gm = m0 + wm + mt * 16 + quad * 4;
                u16x4 pk;
#pragma unroll
                for (int r = 0; r < 4; r++) pk[r] = f2h((acc[mt][nt][r] + bs) * scale);
                *(u16x4*)&C16h[(size_t)gn * M + gm] = pk;
            } else {
#pragma unroll
                for (int r = 0; r < 4; r++) {
                    int gm = m0 + wm + mt * 16 + quad * 4 + r;
                    float v = (acc[mt][nt][r] + bs) * scale;
                    if constexpr (OUTMODE == 0) {
                        Cf[(size_t)gm * N + gn] = v;
                    } else {
                        u16 hh = f2bf(v);
                        C16h[(size_t)gm * N + gn] = hh;
                        C16l[(size_t)gm * N + gn] = f2bf(v - bf2f(hh));
                    }
                }
            }
        }
}

// ---------------- fused Q/K/V projections (grid.z selects) ----------------
__global__ __launch_bounds__(256, 3) void k_qkv(
    const u16* __restrict__ qh, const u16* __restrict__ ql,
    const u16* __restrict__ kh, const u16* __restrict__ kl,
    const u16* __restrict__ vh,
    const u16* __restrict__ WqTh, const u16* __restrict__ WqTl,
    const u16* __restrict__ WkTh, const u16* __restrict__ WkTl,
    const u16* __restrict__ WvT,
    const float* __restrict__ bq, const float* __restrict__ bk, const float* __restrict__ bv,
    u16* __restrict__ Qh, u16* __restrict__ Ql2,
    u16* __restrict__ Kh, u16* __restrict__ Kl2, u16* __restrict__ Vt) {
    __shared__ u16 As[2][128 * 32];
    __shared__ u16 Bs[2][128 * 32];
    int z = blockIdx.z;
    if (z == 0)
        gemm_body<1, 0, 2>(qh, ql, WqTh, WqTl, bq, Qh, Ql2, nullptr, QSCALE,
                           As[0], As[1], Bs[0], Bs[1]);
    else if (z == 1)
        gemm_body<1, 0, 2>(kh, kl, WkTh, WkTl, bk, Kh, Kl2, nullptr, 1.0f,
                           As[0], As[1], Bs[0], Bs[1]);
    else
        gemm_body<0, 1, 1>(vh, nullptr, WvT, nullptr, bv, Vt, nullptr, nullptr, 1.0f,
                           As[0], As[1], Bs[0], Bs[1]);
}

// ---------------- output projection: ctx(fp16) @ WoT(fp16) + bo -> f32 ----------------
__global__ __launch_bounds__(256, 3) void k_out(
    const u16* __restrict__ ctx, const u16* __restrict__ WoT,
    const float* __restrict__ bo, float* __restrict__ out) {
    __shared__ u16 As[128 * 32];
    __shared__ u16 Bs[128 * 32];
    gemm_body<0, 1, 0>(ctx, nullptr, WoT, nullptr, bo, nullptr, nullptr, out, 1.0f,
                       As, nullptr, Bs, nullptr);
}

// ---------------- flash attention: 32x32 MFMA, in-register softmax (T12) ------------
// r21: r20's split-t+merge REGRESSED 82.5->302us (device-scope threadfence forces
// 33.6MB partials through HBM; dur == hbm_bytes/BW exactly). Reverted to the
// r17/r19 kernel (measured 82.2-83.0us): K+V gld_lds-staged dbuf with
// inverse-swizzled source (rule #21), 32x32 MFMA, branchless in-register
// softmax, T12 cvt_pkrtz+permlane32_swap P path. This state is a verified
// local optimum: no pipe saturated (Mfma 35, VALU 37, LDS ~37%, HBM 4%),
// occupancy grid-limited (512 blocks = 2/CU); split-t, V-direct, and defer-max
// all measured worse. Lesson: cross-block rendezvous costs device-scope
// visibility = HBM roundtrip of all partial state.
__global__ __launch_bounds__(256, 2) void k_attn(
    const u16* __restrict__ Qh, const u16* __restrict__ Ql,
    const u16* __restrict__ Kh, const u16* __restrict__ Kl,
    const u16* __restrict__ Vt, u16* __restrict__ ctx) {
    const int bh = blockIdx.x;
    const int b = bh >> 4, h = bh & 15;
    const int q0 = blockIdx.y * 128;
    const int rowBase = b * Ss + q0;
    const int hc = h * 64;

    __shared__ u16 Ks[2][2][64 * 64];  // [buf][plane][row*64 + chunk] (32 KB)
    __shared__ u16 Vs[2][64 * 64];     // [buf][row*64 + chunk] fp16 (16 KB)

    const int tid = threadIdx.x;
    const int wave = tid >> 6, lane = tid & 63;
    const int l31 = lane & 31, hi = lane >> 5;
    const int swl = l31 & 7;

    // ---- staging: linear LDS dest, inverse-swizzled global source (rule #21)
    const int c0 = tid, c1 = tid + 256;
    const int srow0 = c0 >> 3, sj0 = (c0 & 7) ^ (srow0 & 7);
    const int srow1 = c1 >> 3, sj1 = (c1 & 7) ^ (srow1 & 7);

    auto stage = [&](int t0, int bf) {
        const size_t kb = (size_t)(b * Ss + t0) * Ee + hc;
        const size_t vb0 = (size_t)(hc + srow0) * Mrows + b * Ss + t0;
        const size_t vb1 = (size_t)(hc + srow1) * Mrows + b * Ss + t0;
        gld16(Kh + kb + (size_t)srow0 * Ee + sj0 * 8, &Ks[bf][0][c0 * 8]);
        gld16(Kh + kb + (size_t)srow1 * Ee + sj1 * 8, &Ks[bf][0][c1 * 8]);
        gld16(Kl + kb + (size_t)srow0 * Ee + sj0 * 8, &Ks[bf][1][c0 * 8]);
        gld16(Kl + kb + (size_t)srow1 * Ee + sj1 * 8, &Ks[bf][1][c1 * 8]);
        gld16(Vt + vb0 + sj0 * 8, &Vs[bf][c0 * 8]);
        gld16(Vt + vb1 + sj1 * 8, &Vs[bf][c1 * 8]);
    };

    // loop-invariant Q B-frags: col q = l31, k = d = ks*16 + hi*8 + e
    s16x8 bqh[4], bql[4];
    {
        const size_t qoff = (size_t)(rowBase + wave * 32 + l31) * Ee + hc + hi * 8;
#pragma unroll
        for (int ks = 0; ks < 4; ks++) {
            bqh[ks] = *(const s16x8*)(Qh + qoff + ks * 16);
            bql[ks] = *(const s16x8*)(Ql + qoff + ks * 16);
        }
    }

    f32x16 o[2];   // [dt]: O^T row d = (r&3)+8*(r>>2)+4*hi+32*dt, col q = l31
    o[0] = (f32x16)0.0f;
    o[1] = (f32x16)0.0f;
    float m_ = -1e30f, l_ = 0.f;

    stage(0, 0);
    __syncthreads();

    for (int t0 = 0; t0 < Ss; t0 += 64) {
        const int p = (t0 >> 6) & 1;
        if (t0 + 64 < Ss) stage(t0 + 64, p ^ 1);

        const u16* Kp = &Ks[p][0][0];
        const u16* Vp = &Vs[p][0];

        // S^T = K.Q^T (split): st[mt] row t = crow(r,hi)+32*mt, col q = l31
        f32x16 st[2];
        st[0] = (f32x16)0.0f;
        st[1] = (f32x16)0.0f;
        __builtin_amdgcn_s_setprio(1);
#pragma unroll
        for (int mt = 0; mt < 2; mt++) {
            const int rb = (mt * 32 + l31) * 64;
#pragma unroll
            for (int ks = 0; ks < 4; ks++) {
                const int sj = ((2 * ks + hi) ^ swl) * 8;
                s16x8 akh = *(const s16x8*)(Kp + rb + sj);
                s16x8 akl = *(const s16x8*)(Kp + rb + sj + 4096);
                st[mt] = MFMA32_BF(akh, bqh[ks], st[mt]);
                st[mt] = MFMA32_BF(akh, bql[ks], st[mt]);
                st[mt] = MFMA32_BF(akl, bqh[ks], st[mt]);
            }
        }
        __builtin_amdgcn_s_setprio(0);

        // online softmax: q = l31 (lane-local), partner rows live in lane^32
        float tmax = st[0][0];
#pragma unroll
        for (int mt = 0; mt < 2; mt++)
#pragma unroll
            for (int r = 0; r < 16; r++) tmax = fmaxf(tmax, st[mt][r]);
        tmax = fmaxf(tmax, __shfl_xor(tmax, 32));
        float mnew = fmaxf(m_, tmax);
        float al = ex2(m_ - mnew);
        m_ = mnew;
        float psum = 0.f;
#pragma unroll
        for (int mt = 0; mt < 2; mt++)
#pragma unroll
            for (int r = 0; r < 16; r++) {
                st[mt][r] = ex2(st[mt][r] - mnew);
                psum += st[mt][r];
            }
        psum += __shfl_xor(psum, 32);
        l_ = l_ * al + psum;
        o[0] *= al;
        o[1] *= al;

        // P -> PV B-frags in registers: 16 cvt_pkrtz + 8 permlane32_swap
        s16x8 pa[4];
#pragma unroll
        for (int kt = 0; kt < 4; kt++) {
            const int G0 = 2 * kt, G1 = 2 * kt + 1;
            const int m0_ = G0 >> 2, r0_ = (G0 & 3) * 4;
            const int m1_ = G1 >> 2, r1_ = (G1 & 3) * 4;
            u32 wA0 = pkrtz(st[m0_][r0_ + 0], st[m0_][r0_ + 1]);
            u32 wB0 = pkrtz(st[m0_][r0_ + 2], st[m0_][r0_ + 3]);
            u32 wA1 = pkrtz(st[m1_][r1_ + 0], st[m1_][r1_ + 1]);
            u32 wB1 = pkrtz(st[m1_][r1_ + 2], st[m1_][r1_ + 3]);
            u32x2 rA = __builtin_amdgcn_permlane32_swap(wA0, wA1, false, false);
            u32x2 rB = __builtin_amdgcn_permlane32_swap(wB0, wB1, false, false);
            u32x4 w;
            w[0] = rA[0]; w[1] = rB[0]; w[2] = rA[1]; w[3] = rB[1];
            pa[kt] = __builtin_bit_cast(s16x8, w);
        }

        // O^T += V^T . P^T : A = V^T (row d, k t), B = pa (col q, k t)
        __builtin_amdgcn_s_setprio(1);
#pragma unroll
        for (int dt = 0; dt < 2; dt++) {
            const int rbv = (dt * 32 + l31) * 64;
#pragma unroll
            for (int kt = 0; kt < 4; kt++) {
                const int sj = ((2 * kt + hi) ^ swl) * 8;
                s16x8 av = *(const s16x8*)(Vp + rbv + sj);
                o[dt] = MFMA32_F16(av, pa[kt], o[dt]);
            }
        }
        __builtin_amdgcn_s_setprio(0);

        __syncthreads();   // drains this iter's stage (vmcnt(0)) + flips buffer
    }

    // epilogue: ctx[q][hc+d] fp16, d = j + 8g + 4hi + 32dt -> 8B packed stores
    float inv = 1.0f / l_;
    const size_t obase = (size_t)(rowBase + wave * 32 + l31) * Ee + hc + hi * 4;
#pragma unroll
    for (int dt = 0; dt < 2; dt++)
#pragma unroll
        for (int g = 0; g < 4; g++) {
            u32x2 pk;
            pk[0] = pkrtz(o[dt][g * 4 + 0] * inv, o[dt][g * 4 + 1] * inv);
            pk[1] = pkrtz(o[dt][g * 4 + 2] * inv, o[dt][g * 4 + 3] * inv);
            *(u32x2*)&ctx[obase + dt * 32 + g * 8] = pk;
        }
}

extern "C" void kernel_launch(void* const* d_in, const int* in_sizes, int n_in,
                              void* d_out, int out_size, void* d_ws, size_t ws_size,
                              hipStream_t stream) {
    const float* q   = (const float*)d_in[0];
    const float* kin = (const float*)d_in[1];
    const float* v   = (const float*)d_in[2];
    const float* Wq  = (const float*)d_in[3];
    const float* Wk  = (const float*)d_in[4];
    const float* Wv  = (const float*)d_in[5];
    const float* bq  = (const float*)d_in[6];
    const float* bk  = (const float*)d_in[7];
    const float* bv  = (const float*)d_in[8];
    const float* Wo  = (const float*)d_in[9];
    const float* bo  = (const float*)d_in[10];

    u16* ws = (u16*)d_ws;
    u16 *qh = ws,          *ql = ws + NE,     *kh = ws + 2 * NE, *kl = ws + 3 * NE;
    u16 *vh = ws + 4 * NE;
    u16 *Qh = ws + 5 * NE, *Ql = ws + 6 * NE, *Kh = ws + 7 * NE, *Kl = ws + 8 * NE;
    u16 *Vt = ws + 9 * NE, *ctx = ws + 10 * NE;
    u16 *WqTh = ws + 11 * NE;
    u16 *WqTl = WqTh + WN, *WkTh = WqTh + 2 * WN, *WkTl = WqTh + 3 * WN;
    u16 *WvT = WqTh + 4 * WN, *WoT = WqTh + 5 * WN;

    dim3 b256(256);
    k_prep<<<dim3(6144 + 1024), b256, 0, stream>>>(q, kin, v, qh, ql, kh, kl, vh,
                                                   Wq, Wk, Wv, Wo,
                                                   WqTh, WqTl, WkTh, WkTl, WvT, WoT);

    k_qkv<<<dim3(8, 32, 3), b256, 0, stream>>>(qh, ql, kh, kl, vh,
                                               WqTh, WqTl, WkTh, WkTl, WvT,
                                               bq, bk, bv, Qh, Ql, Kh, Kl, Vt);

    k_attn<<<dim3(Bb * Hh, Ss / 128), b256, 0, stream>>>(Qh, Ql, Kh, Kl, Vt, ctx);

    k_out<<<dim3(8, 32), b256, 0, stream>>>(ctx, WoT, bo, (float*)d_out);
}

// Round 16
// 274.199 us; speedup vs baseline: 1.8165x; 1.0173x over previous
//
#include <hip/hip_runtime.h>
#include <hip/hip_bf16.h>

typedef unsigned short u16;
typedef unsigned int   u32;
typedef _Float16 f16;
typedef __attribute__((ext_vector_type(4))) float f32x4;
typedef __attribute__((ext_vector_type(16))) float f32x16;
typedef __attribute__((ext_vector_type(8))) short s16x8;
typedef __attribute__((ext_vector_type(8))) f16 f16x8;
typedef __attribute__((ext_vector_type(2))) __fp16 fp16x2;
typedef __attribute__((ext_vector_type(4))) u16 u16x4;
typedef __attribute__((ext_vector_type(8))) u16 u16x8;
typedef __attribute__((ext_vector_type(2))) u32 u32x2;
typedef __attribute__((ext_vector_type(4))) u32 u32x4;

#define DI __device__ __forceinline__

static constexpr int Bb = 2, Ss = 2048, Hh = 16, Dd = 64, Ee = 1024;
static constexpr int Mrows = Bb * Ss;              // 4096
static constexpr size_t NE = (size_t)Mrows * Ee;   // 4 M elems
static constexpr size_t WN = (size_t)Ee * Ee;      // 1 M elems
static constexpr float QSCALE = 0.125f * 1.44269504088896f;  // 1/8 * log2(e)

DI float bf2f(u16 h) { u32 u = ((u32)h) << 16; return __builtin_bit_cast(float, u); }
DI u16 f2bf(float f) {
    u32 u = __builtin_bit_cast(u32, f);
    u32 r = (u + 0x7FFFu + ((u >> 16) & 1u)) >> 16;
    return (u16)r;
}
DI u16 f2h(float f) { f16 h = (f16)f; return __builtin_bit_cast(u16, h); }
DI u32 pkrtz(float a, float b) {
    fp16x2 r = __builtin_amdgcn_cvt_pkrtz(a, b);
    return __builtin_bit_cast(u32, r);
}
DI float ex2(float x) { return __builtin_amdgcn_exp2f(x); }

#define MFMA_BF(a, b, c) __builtin_amdgcn_mfma_f32_16x16x32_bf16((a), (b), (c), 0, 0, 0)
#define MFMA_F16(a, b, c) __builtin_amdgcn_mfma_f32_16x16x32_f16( \
    __builtin_bit_cast(f16x8, (a)), __builtin_bit_cast(f16x8, (b)), (c), 0, 0, 0)
#define MFMA32_BF(a, b, c) __builtin_amdgcn_mfma_f32_32x32x16_bf16((a), (b), (c), 0, 0, 0)
#define MFMA32_F16(a, b, c) __builtin_amdgcn_mfma_f32_32x32x16_f16( \
    __builtin_bit_cast(f16x8, (a)), __builtin_bit_cast(f16x8, (b)), (c), 0, 0, 0)

// async global->LDS, 16B per lane (LDS dest is wave-uniform base + lane*16)
DI void gld16(const u16* g, u16* l) {
    __builtin_amdgcn_global_load_lds((const __attribute__((address_space(1))) void*)g,
                                     (__attribute__((address_space(3))) void*)l, 16, 0, 0);
}

// ---------------- merged prep: split3 (bid<6144) + wprep (bid>=6144) ----------------
__global__ __launch_bounds__(256) void k_prep(
    const float* __restrict__ q, const float* __restrict__ k, const float* __restrict__ v,
    u16* __restrict__ qh, u16* __restrict__ ql,
    u16* __restrict__ kh, u16* __restrict__ kl, u16* __restrict__ vh,
    const float* __restrict__ Wq, const float* __restrict__ Wk,
    const float* __restrict__ Wv, const float* __restrict__ Wo,
    u16* __restrict__ WqTh, u16* __restrict__ WqTl,
    u16* __restrict__ WkTh, u16* __restrict__ WkTl,
    u16* __restrict__ WvT, u16* __restrict__ WoT) {
    __shared__ float Ts[64 * 65];
    const int bid = blockIdx.x;
    if (bid < 6144) {
        const int y = bid >> 11;
        size_t i = ((size_t)(bid & 2047) * 256 + threadIdx.x) * 8;
        if (y == 2) {
            f32x4 a = *(const f32x4*)(v + i);
            f32x4 b2 = *(const f32x4*)(v + i + 4);
            u16x8 o_;
#pragma unroll
            for (int j = 0; j < 4; j++) { o_[j] = f2h(a[j]); o_[4 + j] = f2h(b2[j]); }
            *(u16x8*)(vh + i) = o_;
            return;
        }
        const float* s = y ? k : q;
        u16* h = y ? kh : qh;
        u16* l = y ? kl : ql;
        f32x4 a = *(const f32x4*)(s + i);
        f32x4 b2 = *(const f32x4*)(s + i + 4);
        u16x8 oh, ol;
#pragma unroll
        for (int j = 0; j < 4; j++) {
            u16 hh = f2bf(a[j]); oh[j] = hh; ol[j] = f2bf(a[j] - bf2f(hh));
            u16 h2 = f2bf(b2[j]); oh[4 + j] = h2; ol[4 + j] = f2bf(b2[j] - bf2f(h2));
        }
        *(u16x8*)(h + i) = oh;
        *(u16x8*)(l + i) = ol;
        return;
    }
    const int t2 = bid - 6144;
    const int y = t2 >> 8;
    const int bx = t2 & 255;
    const int ti = bx >> 4, tj = bx & 15;
    const float* W = (y == 0) ? Wq : (y == 1) ? Wk : (y == 2) ? Wv : Wo;
    const int t = threadIdx.x;
    const int col = t & 63, rb = (t >> 6) * 16;
#pragma unroll
    for (int rr = 0; rr < 16; rr++) {
        int row = rb + rr;
        float vv = (y < 3) ? W[(size_t)ti * 65536 + (size_t)(tj * 64 + row) * 64 + col]
                           : W[(size_t)(tj * 64 + row) * Ee + ti * 64 + col];
        Ts[row * 65 + col] = vv;
    }
    __syncthreads();
#pragma unroll
    for (int rr = 0; rr < 16; rr++) {
        int orow = rb + rr;
        int ocol = col;
        float vv = Ts[ocol * 65 + orow];
        size_t oidx = (size_t)(ti * 64 + orow) * Ee + tj * 64 + ocol;
        if (y == 0) {
            u16 hh = f2bf(vv); WqTh[oidx] = hh; WqTl[oidx] = f2bf(vv - bf2f(hh));
        } else if (y == 1) {
            u16 hh = f2bf(vv); WkTh[oidx] = hh; WkTl[oidx] = f2bf(vv - bf2f(hh));
        } else if (y == 2) {
            WvT[oidx] = f2h(vv);
        } else {
            WoT[oidx] = f2h(vv);
        }
    }
}

// ---------------- GEMM body, 128(M) x 128(N) tile (m97 structure) ----------------
template <int SPLIT, int F16, int OUTMODE>
DI void gemm_body(const u16* __restrict__ Ah, const u16* __restrict__ Al,
                  const u16* __restrict__ Bh, const u16* __restrict__ Bl,
                  const float* __restrict__ bias,
                  u16* __restrict__ C16h, u16* __restrict__ C16l, float* __restrict__ Cf,
                  float scale, u16* As0, u16* As1, u16* Bs0, u16* Bs1) {
    constexpr int M = Mrows, N = Ee, K = Ee;
    const int tid = threadIdx.x;
    const int wave = tid >> 6, lane = tid & 63;
    const int quad = lane >> 4, l16 = lane & 15;
    const int m0 = blockIdx.y * 128, n0 = blockIdx.x * 128;
    const int wm = (wave >> 1) * 64, wn = (wave & 1) * 64;

    f32x4 acc[4][4];
#pragma unroll
    for (int i = 0; i < 4; i++)
#pragma unroll
        for (int j = 0; j < 4; j++) acc[i][j] = (f32x4)0.0f;

    for (int kk = 0; kk < K; kk += 32) {
        __syncthreads();
#pragma unroll
        for (int i = 0; i < 2; i++) {
            int c = tid + i * 256;
            int row = c >> 2, j = c & 3;
            size_t ga = (size_t)(m0 + row) * K + kk + j * 8;
            gld16(Ah + ga, As0 + c * 8);
            if constexpr (SPLIT) gld16(Al + ga, As1 + c * 8);
            size_t gb = (size_t)(n0 + row) * K + kk + j * 8;
            gld16(Bh + gb, Bs0 + c * 8);
            if constexpr (SPLIT) gld16(Bl + gb, Bs1 + c * 8);
        }
        __syncthreads();

        s16x8 bf[4][2];
#pragma unroll
        for (int nt = 0; nt < 4; nt++) {
            int r = wn + nt * 16 + l16;
            bf[nt][0] = *(const s16x8*)&Bs0[r * 32 + quad * 8];
            if constexpr (SPLIT) bf[nt][1] = *(const s16x8*)&Bs1[r * 32 + quad * 8];
        }
#pragma unroll
        for (int mt = 0; mt < 4; mt++) {
            int r = wm + mt * 16 + l16;
            s16x8 a0 = *(const s16x8*)&As0[r * 32 + quad * 8];
            s16x8 a1;
            if constexpr (SPLIT) a1 = *(const s16x8*)&As1[r * 32 + quad * 8];
#pragma unroll
            for (int nt = 0; nt < 4; nt++) {
                if constexpr (F16) {
                    acc[mt][nt] = MFMA_F16(a0, bf[nt][0], acc[mt][nt]);
                } else {
                    acc[mt][nt] = MFMA_BF(a0, bf[nt][0], acc[mt][nt]);
                    if constexpr (SPLIT) {
                        acc[mt][nt] = MFMA_BF(a0, bf[nt][1], acc[mt][nt]);
                        acc[mt][nt] = MFMA_BF(a1, bf[nt][0], acc[mt][nt]);
                    }
                }
            }
        }
    }

#pragma unroll
    for (int mt = 0; mt < 4; mt++)
#pragma unroll
        for (int nt = 0; nt < 4; nt++) {
            int gn = n0 + wn + nt * 16 + l16;
            float bs = bias[gn];
            if constexpr (OUTMODE == 1) {
                int gm = m0 + wm + mt * 16 + quad * 4;
                u16x4 pk;
#pragma unroll
                for (int r = 0; r < 4; r++) pk[r] = f2h((acc[mt][nt][r] + bs) * scale);
                *(u16x4*)&C16h[(size_t)gn * M + gm] = pk;
            } else {
#pragma unroll
                for (int r = 0; r < 4; r++) {
                    int gm = m0 + wm + mt * 16 + quad * 4 + r;
                    float v = (acc[mt][nt][r] + bs) * scale;
                    if constexpr (OUTMODE == 0) {
                        Cf[(size_t)gm * N + gn] = v;
                    } else {
                        u16 hh = f2bf(v);
                        C16h[(size_t)gm * N + gn] = hh;
                        C16l[(size_t)gm * N + gn] = f2bf(v - bf2f(hh));
                    }
                }
            }
        }
}

// ---------------- fused Q/K/V projections (grid.z selects) ----------------
__global__ __launch_bounds__(256, 3) void k_qkv(
    const u16* __restrict__ qh, const u16* __restrict__ ql,
    const u16* __restrict__ kh, const u16* __restrict__ kl,
    const u16* __restrict__ vh,
    const u16* __restrict__ WqTh, const u16* __restrict__ WqTl,
    const u16* __restrict__ WkTh, const u16* __restrict__ WkTl,
    const u16* __restrict__ WvT,
    const float* __restrict__ bq, const float* __restrict__ bk, const float* __restrict__ bv,
    u16* __restrict__ Qh, u16* __restrict__ Ql2,
    u16* __restrict__ Kh, u16* __restrict__ Kl2, u16* __restrict__ Vt) {
    __shared__ u16 As[2][128 * 32];
    __shared__ u16 Bs[2][128 * 32];
    int z = blockIdx.z;
    if (z == 0)
        gemm_body<1, 0, 2>(qh, ql, WqTh, WqTl, bq, Qh, Ql2, nullptr, QSCALE,
                           As[0], As[1], Bs[0], Bs[1]);
    else if (z == 1)
        gemm_body<1, 0, 2>(kh, kl, WkTh, WkTl, bk, Kh, Kl2, nullptr, 1.0f,
                           As[0], As[1], Bs[0], Bs[1]);
    else
        gemm_body<0, 1, 1>(vh, nullptr, WvT, nullptr, bv, Vt, nullptr, nullptr, 1.0f,
                           As[0], As[1], Bs[0], Bs[1]);
}

// ---------------- output projection: ctx(fp16) @ WoT(fp16) + bo -> f32 ----------------
__global__ __launch_bounds__(256, 3) void k_out(
    const u16* __restrict__ ctx, const u16* __restrict__ WoT,
    const float* __restrict__ bo, float* __restrict__ out) {
    __shared__ u16 As[128 * 32];
    __shared__ u16 Bs[128 * 32];
    gemm_body<0, 1, 0>(ctx, nullptr, WoT, nullptr, bo, nullptr, nullptr, out, 1.0f,
                       As, nullptr, Bs, nullptr);
}

// ---------------- flash attention: 32x32 MFMA + T15 2-deep pipeline -----------------
// r22: r21 state (80.7us) has ~25us of serial-chain exposure (accounted work
// ~55us): QK->softmax->pack->PV strict chain, only 2 waves/SIMD. T15 restructure:
// compute QK(i+1) BEFORE finishing softmax+PV(i) so the independent MFMA/ds_read
// stream (i+1) and VALU stream (i) share the scheduler window. 3-buffer K/V
// rotation (stage(i+2) / QK(i+1) / PV(i) are disjoint mod 3); ping-pong stA/stB
// (static names, rule #20); pointer rotation; branch-free 2x-unrolled loop with
// peeled tail (r16 lesson: no mid-loop branches). LDS 72KB, still 2 blocks/CU
// (grid-limited). Math bit-identical.
__global__ __launch_bounds__(256, 2) void k_attn(
    const u16* __restrict__ Qh, const u16* __restrict__ Ql,
    const u16* __restrict__ Kh, const u16* __restrict__ Kl,
    const u16* __restrict__ Vt, u16* __restrict__ ctx) {
    const int bh = blockIdx.x;
    const int b = bh >> 4, h = bh & 15;
    const int q0 = blockIdx.y * 128;
    const int rowBase = b * Ss + q0;
    const int hc = h * 64;

    __shared__ u16 Ks[3][2][64 * 64];  // [buf][plane][row*64 + chunk] (48 KB)
    __shared__ u16 Vs[3][64 * 64];     // [buf][row*64 + chunk] fp16 (24 KB)

    const int tid = threadIdx.x;
    const int wave = tid >> 6, lane = tid & 63;
    const int l31 = lane & 31, hi = lane >> 5;
    const int swl = l31 & 7;

    // ---- staging: linear LDS dest, inverse-swizzled global source (rule #21)
    const int c0 = tid, c1 = tid + 256;
    const int srow0 = c0 >> 3, sj0 = (c0 & 7) ^ (srow0 & 7);
    const int srow1 = c1 >> 3, sj1 = (c1 & 7) ^ (srow1 & 7);

    auto stage = [&](int t0, u16* Kd, u16* Vd) {
        const size_t kb = (size_t)(b * Ss + t0) * Ee + hc;
        const size_t vb0 = (size_t)(hc + srow0) * Mrows + b * Ss + t0;
        const size_t vb1 = (size_t)(hc + srow1) * Mrows + b * Ss + t0;
        gld16(Kh + kb + (size_t)srow0 * Ee + sj0 * 8, Kd + c0 * 8);
        gld16(Kh + kb + (size_t)srow1 * Ee + sj1 * 8, Kd + c1 * 8);
        gld16(Kl + kb + (size_t)srow0 * Ee + sj0 * 8, Kd + 4096 + c0 * 8);
        gld16(Kl + kb + (size_t)srow1 * Ee + sj1 * 8, Kd + 4096 + c1 * 8);
        gld16(Vt + vb0 + sj0 * 8, Vd + c0 * 8);
        gld16(Vt + vb1 + sj1 * 8, Vd + c1 * 8);
    };

    // loop-invariant Q B-frags: col q = l31, k = d = ks*16 + hi*8 + e
    s16x8 bqh[4], bql[4];
    {
        const size_t qoff = (size_t)(rowBase + wave * 32 + l31) * Ee + hc + hi * 8;
#pragma unroll
        for (int ks = 0; ks < 4; ks++) {
            bqh[ks] = *(const s16x8*)(Qh + qoff + ks * 16);
            bql[ks] = *(const s16x8*)(Ql + qoff + ks * 16);
        }
    }

    f32x16 o[2];   // [dt]: O^T row d = (r&3)+8*(r>>2)+4*hi+32*dt, col q = l31
    o[0] = (f32x16)0.0f;
    o[1] = (f32x16)0.0f;
    float m_ = -1e30f, l_ = 0.f;

    // S^T = K.Q^T (split): st[mt] row t = crow(r,hi)+32*mt, col q = l31
    auto qk = [&](const u16* Kp, f32x16* st) {
        st[0] = (f32x16)0.0f;
        st[1] = (f32x16)0.0f;
        __builtin_amdgcn_s_setprio(1);
#pragma unroll
        for (int mt = 0; mt < 2; mt++) {
            const int rb = (mt * 32 + l31) * 64;
#pragma unroll
            for (int ks = 0; ks < 4; ks++) {
                const int sj = ((2 * ks + hi) ^ swl) * 8;
                s16x8 akh = *(const s16x8*)(Kp + rb + sj);
                s16x8 akl = *(const s16x8*)(Kp + rb + sj + 4096);
                st[mt] = MFMA32_BF(akh, bqh[ks], st[mt]);
                st[mt] = MFMA32_BF(akh, bql[ks], st[mt]);
                st[mt] = MFMA32_BF(akl, bqh[ks], st[mt]);
            }
        }
        __builtin_amdgcn_s_setprio(0);
    };

    // online softmax (branchless) + in-reg P pack + PV, consumes st, updates m/l/o
    auto finish = [&](f32x16* st, const u16* Vp) {
        float tmax = st[0][0];
#pragma unroll
        for (int mt = 0; mt < 2; mt++)
#pragma unroll
            for (int r = 0; r < 16; r++) tmax = fmaxf(tmax, st[mt][r]);
        tmax = fmaxf(tmax, __shfl_xor(tmax, 32));
        float mnew = fmaxf(m_, tmax);
        float al = ex2(m_ - mnew);
        m_ = mnew;
        float psum = 0.f;
#pragma unroll
        for (int mt = 0; mt < 2; mt++)
#pragma unroll
            for (int r = 0; r < 16; r++) {
                st[mt][r] = ex2(st[mt][r] - mnew);
                psum += st[mt][r];
            }
        psum += __shfl_xor(psum, 32);
        l_ = l_ * al + psum;
        o[0] *= al;
        o[1] *= al;

        s16x8 pa[4];
#pragma unroll
        for (int kt = 0; kt < 4; kt++) {
            const int G0 = 2 * kt, G1 = 2 * kt + 1;
            const int m0_ = G0 >> 2, r0_ = (G0 & 3) * 4;
            const int m1_ = G1 >> 2, r1_ = (G1 & 3) * 4;
            u32 wA0 = pkrtz(st[m0_][r0_ + 0], st[m0_][r0_ + 1]);
            u32 wB0 = pkrtz(st[m0_][r0_ + 2], st[m0_][r0_ + 3]);
            u32 wA1 = pkrtz(st[m1_][r1_ + 0], st[m1_][r1_ + 1]);
            u32 wB1 = pkrtz(st[m1_][r1_ + 2], st[m1_][r1_ + 3]);
            u32x2 rA = __builtin_amdgcn_permlane32_swap(wA0, wA1, false, false);
            u32x2 rB = __builtin_amdgcn_permlane32_swap(wB0, wB1, false, false);
            u32x4 w;
            w[0] = rA[0]; w[1] = rB[0]; w[2] = rA[1]; w[3] = rB[1];
            pa[kt] = __builtin_bit_cast(s16x8, w);
        }

        __builtin_amdgcn_s_setprio(1);
#pragma unroll
        for (int dt = 0; dt < 2; dt++) {
            const int rbv = (dt * 32 + l31) * 64;
#pragma unroll
            for (int kt = 0; kt < 4; kt++) {
                const int sj = ((2 * kt + hi) ^ swl) * 8;
                s16x8 av = *(const s16x8*)(Vp + rbv + sj);
                o[dt] = MFMA32_F16(av, pa[kt], o[dt]);
            }
        }
        __builtin_amdgcn_s_setprio(0);
    };

    // buffer roles: A = tile i (PV), B = tile i+1 (QK), C = stage dest (tile i+2)
    u16 *KA = &Ks[0][0][0], *KB = &Ks[1][0][0], *KC = &Ks[2][0][0];
    u16 *VA = &Vs[0][0],    *VB = &Vs[1][0],    *VC = &Vs[2][0];

    stage(0, KA, VA);
    stage(64, KB, VB);
    __syncthreads();

    f32x16 stA[2], stB[2];
    qk(KA, stA);

    for (int i = 0; i < 15; ++i) {
        const int t0 = i * 128;
        // even half: finish tile 2i (stA), QK tile 2i+1 -> stB
        stage(t0 + 128, KC, VC);
        qk(KB, stB);
        finish(stA, VA);
        __syncthreads();
        { u16* t = KA; KA = KB; KB = KC; KC = t; }
        { u16* t = VA; VA = VB; VB = VC; VC = t; }
        // odd half: finish tile 2i+1 (stB), QK tile 2i+2 -> stA
        stage(t0 + 192, KC, VC);
        qk(KB, stA);
        finish(stB, VA);
        __syncthreads();
        { u16* t = KA; KA = KB; KB = KC; KC = t; }
        { u16* t = VA; VA = VB; VB = VC; VC = t; }
    }
    // after loop: KA/VA = tile 30, KB/VB = tile 31 (staged+drained), stA = QK(30)
    qk(KB, stB);       // tile 31
    finish(stA, VA);   // tile 30
    finish(stB, VB);   // tile 31

    // epilogue: ctx[q][hc+d] fp16, d = j + 8g + 4hi + 32dt -> 8B packed stores
    float inv = 1.0f / l_;
    const size_t obase = (size_t)(rowBase + wave * 32 + l31) * Ee + hc + hi * 4;
#pragma unroll
    for (int dt = 0; dt < 2; dt++)
#pragma unroll
        for (int g = 0; g < 4; g++) {
            u32x2 pk;
            pk[0] = pkrtz(o[dt][g * 4 + 0] * inv, o[dt][g * 4 + 1] * inv);
            pk[1] = pkrtz(o[dt][g * 4 + 2] * inv, o[dt][g * 4 + 3] * inv);
            *(u32x2*)&ctx[obase + dt * 32 + g * 8] = pk;
        }
}

extern "C" void kernel_launch(void* const* d_in, const int* in_sizes, int n_in,
                              void* d_out, int out_size, void* d_ws, size_t ws_size,
                              hipStream_t stream) {
    const float* q   = (const float*)d_in[0];
    const float* kin = (const float*)d_in[1];
    const float* v   = (const float*)d_in[2];
    const float* Wq  = (const float*)d_in[3];
    const float* Wk  = (const float*)d_in[4];
    const float* Wv  = (const float*)d_in[5];
    const float* bq  = (const float*)d_in[6];
    const float* bk  = (const float*)d_in[7];
    const float* bv  = (const float*)d_in[8];
    const float* Wo  = (const float*)d_in[9];
    const float* bo  = (const float*)d_in[10];

    u16* ws = (u16*)d_ws;
    u16 *qh = ws,          *ql = ws + NE,     *kh = ws + 2 * NE, *kl = ws + 3 * NE;
    u16 *vh = ws + 4 * NE;
    u16 *Qh = ws + 5 * NE, *Ql = ws + 6 * NE, *Kh = ws + 7 * NE, *Kl = ws + 8 * NE;
    u16 *Vt = ws + 9 * NE, *ctx = ws + 10 * NE;
    u16 *WqTh = ws + 11 * NE;
    u16 *WqTl = WqTh + WN, *WkTh = WqTh + 2 * WN, *WkTl = WqTh + 3 * WN;
    u16 *WvT = WqTh + 4 * WN, *WoT = WqTh + 5 * WN;

    dim3 b256(256);
    k_prep<<<dim3(6144 + 1024), b256, 0, stream>>>(q, kin, v, qh, ql, kh, kl, vh,
                                                   Wq, Wk, Wv, Wo,
                                                   WqTh, WqTl, WkTh, WkTl, WvT, WoT);

    k_qkv<<<dim3(8, 32, 3), b256, 0, stream>>>(qh, ql, kh, kl, vh,
                                               WqTh, WqTl, WkTh, WkTl, WvT,
                                               bq, bk, bv, Qh, Ql, Kh, Kl, Vt);

    k_attn<<<dim3(Bb * Hh, Ss / 128), b256, 0, stream>>>(Qh, Ql, Kh, Kl, Vt, ctx);

    k_out<<<dim3(8, 32), b256, 0, stream>>>(ctx, WoT, bo, (float*)d_out);
}